// Round 16
// baseline (428.665 us; speedup 1.0000x reference)
//
#include <hip/hip_runtime.h>
#include <hip/hip_bf16.h>

#define NA 8192
#define NP 65536
#define WROW 1920

typedef short short8 __attribute__((ext_vector_type(8)));
typedef short short4v __attribute__((ext_vector_type(4)));
typedef float floatx4 __attribute__((ext_vector_type(4)));
typedef unsigned uint3v __attribute__((ext_vector_type(3)));

static __device__ __forceinline__ short f2bf(float f) {
    union { float f; unsigned u; } v; v.f = f;
    unsigned r = v.u + 0x7FFF + ((v.u >> 16) & 1);
    return (short)(r >> 16);
}
static __device__ __forceinline__ float bf2f(short s) {
    union { unsigned u; float f; } v;
    v.u = ((unsigned)(unsigned short)s) << 16;
    return v.f;
}
static __device__ __forceinline__ unsigned char f2fp8(float f) {
    int p = __builtin_amdgcn_cvt_pk_fp8_f32(f, 0.f, 0, false);
    return (unsigned char)(p & 0xFF);
}
static __device__ __forceinline__ float fp82f(unsigned char b) {
    return __builtin_amdgcn_cvt_f32_fp8((int)b, 0);
}
static __device__ __forceinline__ float silu(float v) {
    return v / (1.f + __expf(-v));
}

// swizzle one element: dst[idx] in MFMA-fragment order from src[b][K][N]
static __device__ __forceinline__ void swz(const float* __restrict__ src,
                                           short* __restrict__ dst,
                                           int K, int N, int idx) {
    int kn = K * N;
    int b = idx / kn;
    int r = idx - b * kn;
    int tile = r >> 9, li = r & 511;
    int lane = li >> 3, bb = li & 7;
    int Kt = K >> 5;
    int nt = tile / Kt, kt = tile - nt * Kt;
    int k = kt * 32 + (lane >> 4) * 8 + bb;
    int n = nt * 16 + (lane & 15);
    dst[idx] = f2bf(src[b * kn + k * N + n]);
}

// ---------------- all weight converts in one launch ----------------
__global__ __launch_bounds__(256) void k_tconv_all(const float* __restrict__ iW1,
                                                   const float* __restrict__ iW2,
                                                   const float* __restrict__ mWv,
                                                   const float* __restrict__ mW1,
                                                   const float* __restrict__ mW2,
                                                   const float* __restrict__ fW,
                                                   short* __restrict__ W1t,
                                                   short* __restrict__ W2t,
                                                   short* __restrict__ Wvt,
                                                   short* __restrict__ mW1t,
                                                   short* __restrict__ mW2t,
                                                   short* __restrict__ fWt) {
    int idx = blockIdx.x * 256 + threadIdx.x;
    if (idx < 81920)       { swz(iW1, W1t, 128, 128, idx); return; }
    idx -= 81920;
    if (idx < 245760)      { swz(iW2, W2t, 128, 384, idx); return; }
    idx -= 245760;
    if (idx < 163840)      { swz(mWv, Wvt, 128, 256, idx); return; }
    idx -= 163840;
    if (idx < 163840)      { swz(mW1, mW1t, 256, 128, idx); return; }
    idx -= 163840;
    if (idx < 245760)      { swz(mW2, mW2t, 128, 384, idx); return; }
    idx -= 245760;
    if (idx < 61440) {
        int b = idx / 12288;
        int r = idx - b * 12288;
        int nt = r >> 9;
        int li = r & 511;
        int lane = li >> 3, bb = li & 7;
        int k = (lane >> 4) * 8 + bb;
        int n = nt * 16 + (lane & 15);
        fWt[idx] = (k < 20) ? f2bf(fW[k * WROW + b * 384 + n]) : (short)0;
    }
}

// ---------------- init (+ CSR pad rows) ----------------
// xmu record (12B per (atom,feature)): {x0,x1,x2,pad, mu0, mu1, mu2, pad2}
__global__ __launch_bounds__(256) void k_init(const float* __restrict__ feat,
                                              float* __restrict__ q,
                                              float* __restrict__ mu,
                                              short* __restrict__ q_bf,
                                              unsigned* __restrict__ xmu_u,
                                              int* __restrict__ counts,
                                              int* __restrict__ cursor,
                                              float* __restrict__ cut_csr,
                                              short* __restrict__ rbf_c) {
    int idx = blockIdx.x * 256 + threadIdx.x;     // 0 .. NA*384-1
    if (idx < NA * 128) { float v = feat[idx]; q[idx] = v; q_bf[idx] = f2bf(v); }
    mu[idx] = 0.f;
    xmu_u[idx] = 0;                               // NA*128*12 bytes == NA*384 uints
    if (idx < NA) { counts[idx] = 0; cursor[idx] = 0; }
    if (idx < 16) {
        cut_csr[NP + idx] = 0.f;
        #pragma unroll
        for (int k = 0; k < 32; ++k) rbf_c[(NP + idx) * 32 + k] = 0;
    }
}

// ---------------- CSR build ----------------
__global__ __launch_bounds__(256) void k_hist(const int* __restrict__ idx_i,
                                              int* __restrict__ counts) {
    int p = blockIdx.x * 256 + threadIdx.x;
    if (p < NP) atomicAdd(&counts[idx_i[p]], 1);
}

__global__ __launch_bounds__(1024) void k_scan(const int* __restrict__ counts,
                                               int* __restrict__ offs) {
    __shared__ int sums[1024];
    int t = threadIdx.x;
    int local[8];
    int s = 0;
    #pragma unroll
    for (int k = 0; k < 8; ++k) { local[k] = s; s += counts[t * 8 + k]; }
    sums[t] = s;
    __syncthreads();
    for (int off = 1; off < 1024; off <<= 1) {
        int v = sums[t];
        int u = (t >= off) ? sums[t - off] : 0;
        __syncthreads();
        sums[t] = v + u;
        __syncthreads();
    }
    int base = (t > 0) ? sums[t - 1] : 0;
    #pragma unroll
    for (int k = 0; k < 8; ++k) offs[t * 8 + k] = base + local[k];
    if (t == 1023) offs[NA] = sums[1023];
}

// fill + prep fused: scatter pair p to CSR slot e and write all per-pair data.
__global__ __launch_bounds__(256) void k_fillprep(const int* __restrict__ idx_i,
                                                  const int* __restrict__ idx_j,
                                                  const int* __restrict__ offs,
                                                  int* __restrict__ cursor,
                                                  const float* __restrict__ cut,
                                                  const float* __restrict__ dist,
                                                  const float* __restrict__ vec,
                                                  const float* __restrict__ rbfs,
                                                  int* __restrict__ jcsr,
                                                  float* __restrict__ cut_csr,
                                                  float4* __restrict__ dir_csr,
                                                  short* __restrict__ rbf_c) {
    int p = blockIdx.x * 256 + threadIdx.x;
    if (p >= NP) return;
    int i = idx_i[p];
    int pos = atomicAdd(&cursor[i], 1);
    int e = offs[i] + pos;
    jcsr[e] = idx_j[p];
    float c = cut[p];
    cut_csr[e] = c;
    float invd = 1.f / dist[p];
    float4 d;
    d.x = vec[p * 3 + 0] * invd;
    d.y = vec[p * 3 + 1] * invd;
    d.z = vec[p * 3 + 2] * invd;
    d.w = 0.f;
    dir_csr[e] = d;
    #pragma unroll
    for (int k = 0; k < 20; ++k) rbf_c[e * 32 + k] = f2bf(rbfs[p * 20 + k] * c);
    #pragma unroll
    for (int k = 20; k < 32; ++k) rbf_c[e * 32 + k] = 0;
}

// ---------------- K1 (MFMA): x = silu(q@W1+b1)@W2+b2 -> xmu x-bytes (block 0 only) ----------------
__global__ __launch_bounds__(256) void k_x(const short* __restrict__ q_bf,
                                           const short* __restrict__ W1sw,
                                           const short* __restrict__ W2sw,
                                           const float* __restrict__ b1,
                                           const float* __restrict__ b2,
                                           unsigned char* __restrict__ xmu) {
    __shared__ __align__(16) short qtile[16 * 136];
    __shared__ __align__(16) short hs[16 * 136];
    int t = threadIdx.x;
    int wv = t >> 6, lane = t & 63, quad = lane >> 4, l16 = lane & 15;
    int a0 = blockIdx.x * 16;

    #pragma unroll
    for (int it = 0; it < 2; ++it) {
        int c = it * 256 + t;
        int row = c >> 5, col4 = c & 31;
        *(short4v*)(qtile + row * 136 + col4 * 4) =
            *(const short4v*)(q_bf + (a0 + row) * 128 + col4 * 4);
    }
    __syncthreads();

    floatx4 acc0 = {0.f, 0.f, 0.f, 0.f}, acc1 = {0.f, 0.f, 0.f, 0.f};
    #pragma unroll
    for (int kk = 0; kk < 4; ++kk) {
        short8 a  = *(const short8*)(qtile + l16 * 136 + kk * 32 + quad * 8);
        short8 b0 = *(const short8*)(W1sw + ((wv * 2 + 0) * 4 + kk) * 512 + lane * 8);
        short8 bq = *(const short8*)(W1sw + ((wv * 2 + 1) * 4 + kk) * 512 + lane * 8);
        acc0 = __builtin_amdgcn_mfma_f32_16x16x32_bf16(a, b0, acc0, 0, 0, 0);
        acc1 = __builtin_amdgcn_mfma_f32_16x16x32_bf16(a, bq, acc1, 0, 0, 0);
    }
    __syncthreads();
    {
        int n0 = wv * 32 + l16;
        float bia0 = b1[n0], bia1 = b1[n0 + 16];
        #pragma unroll
        for (int r = 0; r < 4; ++r) {
            int m = quad * 4 + r;
            hs[m * 136 + n0]      = f2bf(silu(acc0[r] + bia0));
            hs[m * 136 + n0 + 16] = f2bf(silu(acc1[r] + bia1));
        }
    }
    __syncthreads();
    floatx4 acc[6];
    #pragma unroll
    for (int jj = 0; jj < 6; ++jj) acc[jj] = {0.f, 0.f, 0.f, 0.f};
    #pragma unroll
    for (int kk = 0; kk < 4; ++kk) {
        short8 a = *(const short8*)(hs + l16 * 136 + kk * 32 + quad * 8);
        #pragma unroll
        for (int jj = 0; jj < 6; ++jj) {
            short8 b = *(const short8*)(W2sw + ((wv * 6 + jj) * 4 + kk) * 512 + lane * 8);
            acc[jj] = __builtin_amdgcn_mfma_f32_16x16x32_bf16(a, b, acc[jj], 0, 0, 0);
        }
    }
    #pragma unroll
    for (int jj = 0; jj < 6; ++jj) {
        int n = wv * 96 + jj * 16 + l16;
        float bia = b2[n];
        #pragma unroll
        for (int r = 0; r < 4; ++r) {
            int m = quad * 4 + r;
            xmu[(size_t)((a0 + m) * 128 + (n & 127)) * 12 + (n >> 7)] =
                f2fp8(acc[jj][r] + bia);
        }
    }
}

// ---------------- K2: 2 atoms/block gather -> bf16 deltas ----------------
// R16: descriptor tile covers the CONTIGUOUS CSR range of two atoms (~16 pairs
// fills the 16-row tile vs ~8 before: half the phase-1 MFMA/loads per pair).
// Half h owns atom 2*blk+h and walks its own stride-1 subrange; no cross-half
// merge needed (pm LDS + barrier deleted). Phase 2 = R13's proven rolling
// depth-1 prefetch on the interleaved 12B xmu record.
__global__ __launch_bounds__(256, 6) void k_gather(const unsigned char* __restrict__ xmu,
                                                   const short* __restrict__ rbf_c,
                                                   const short* __restrict__ fWt,   // swizzled
                                                   const float* __restrict__ fbp,   // fb + bo
                                                   const int* __restrict__ jcsr,
                                                   const float* __restrict__ cut_csr,
                                                   const float4* __restrict__ dir_csr,
                                                   const int* __restrict__ offs,
                                                   short* __restrict__ dqg,
                                                   short* __restrict__ dmug) {
    __shared__ short dlds[16 * 392];
    int blk = blockIdx.x;                       // 0..4095
    int t = threadIdx.x;
    int h = t >> 7;                             // which atom of the two
    int f = t & 127;                            // feature column
    int wv = t >> 6, lane = t & 63, quad = lane >> 4, l16 = lane & 15;
    int i = blk * 2 + h;
    int start2 = offs[blk * 2], end2 = offs[blk * 2 + 2];
    int start = offs[i], end = offs[i + 1];
    float qa = 0.f, m0a = 0.f, m1a = 0.f, m2a = 0.f;

    for (int e0 = start2; e0 < end2; e0 += 16) {
        if (e0 > start2) __syncthreads();       // protect dlds reuse
        // ---- phase 1: descriptors for CSR rows e0..e0+15 (4 waves x 6 n-tiles)
        short8 a = *(const short8*)(rbf_c + (e0 + l16) * 32 + quad * 8);
        float c0 = cut_csr[e0 + quad * 4 + 0];
        float c1 = cut_csr[e0 + quad * 4 + 1];
        float c2 = cut_csr[e0 + quad * 4 + 2];
        float c3 = cut_csr[e0 + quad * 4 + 3];
        #pragma unroll
        for (int nt = 0; nt < 6; ++nt) {
            int col = wv * 96 + nt * 16 + l16;
            short8 bfr = *(const short8*)(fWt + (wv * 6 + nt) * 512 + lane * 8);
            floatx4 z = {0.f, 0.f, 0.f, 0.f};
            floatx4 acc = __builtin_amdgcn_mfma_f32_16x16x32_bf16(a, bfr, z, 0, 0, 0);
            float fbv = fbp[col];
            dlds[(quad * 4 + 0) * 392 + col] = f2bf(acc[0] + fbv * c0);
            dlds[(quad * 4 + 1) * 392 + col] = f2bf(acc[1] + fbv * c1);
            dlds[(quad * 4 + 2) * 392 + col] = f2bf(acc[2] + fbv * c2);
            dlds[(quad * 4 + 3) * 392 + col] = f2bf(acc[3] + fbv * c3);
        }
        __syncthreads();
        // ---- phase 2: half h walks its atom's pairs inside this tile, depth-1 prefetch
        int lo = (start > e0) ? start : e0;
        int hi = (end < e0 + 16) ? end : (e0 + 16);
        if (lo < hi) {
            int jA = jcsr[lo];
            float4 dirA = dir_csr[lo];
            uint3v recA = *(const uint3v*)(xmu + (size_t)jA * 1536 + f * 12);
            for (int e = lo; e < hi; ++e) {
                uint3v rec = recA;
                float4 cdir = dirA;
                if (e + 1 < hi) {
                    int jn = jcsr[e + 1];
                    dirA = dir_csr[e + 1];
                    recA = *(const uint3v*)(xmu + (size_t)jn * 1536 + f * 12);
                }
                float x0 = fp82f((unsigned char)(rec.x & 0xFF));
                float x1 = fp82f((unsigned char)((rec.x >> 8) & 0xFF));
                float x2 = fp82f((unsigned char)((rec.x >> 16) & 0xFF));
                float u0 = bf2f((short)(rec.y & 0xFFFF));
                float u1 = bf2f((short)(rec.y >> 16));
                float u2 = bf2f((short)(rec.z & 0xFFFF));
                int le = e - e0;
                float wa = bf2f(dlds[le * 392 + f]);
                float wb = bf2f(dlds[le * 392 + 128 + f]);
                float wc = bf2f(dlds[le * 392 + 256 + f]);
                qa += x0 * wa;
                float xb = x1 * wb;
                float xc = x2 * wc;
                m0a += xb * cdir.x + xc * u0;
                m1a += xb * cdir.y + xc * u1;
                m2a += xb * cdir.z + xc * u2;
            }
        }
    }
    // ---- commit: each half owns its atom, no merge
    dqg[i * 128 + f]             = f2bf(qa);
    dmug[(i * 3 + 0) * 128 + f]  = f2bf(m0a);
    dmug[(i * 3 + 1) * 128 + f]  = f2bf(m1a);
    dmug[(i * 3 + 2) * 128 + f]  = f2bf(m2a);
}

// ---------------- K3 (MFMA): gather-commit + mixv + mix2 + next-block x-MLP ----------------
__global__ __launch_bounds__(512, 6) void k_mixx(const float* __restrict__ mu_ro,
                                                 const short* __restrict__ dmug,
                                                 const float* __restrict__ q_ro,
                                                 const short* __restrict__ dqg,
                                                 const short* __restrict__ Wvsw,
                                                 const short* __restrict__ W1sw,
                                                 const short* __restrict__ W2sw,
                                                 const float* __restrict__ b1,
                                                 const float* __restrict__ b2,
                                                 float* __restrict__ q,
                                                 float* __restrict__ mu,
                                                 unsigned char* __restrict__ xmu,
                                                 const short* __restrict__ xW1sw,
                                                 const short* __restrict__ xW2sw,
                                                 const float* __restrict__ xb1,
                                                 const float* __restrict__ xb2,
                                                 int do_x) {
    __shared__ __align__(16) char smem[51968];
    short* ms    = (short*)(smem);            // [48][136] post-gather mu (bf16)
    short* qtile = (short*)(smem + 13056);    // [16][136] post-gather q (then post-mix q)
    short* Vv    = (short*)(smem + 17408);    // [48][136] muV
    short* hs    = (short*)(smem + 17408);    // [16][136] alias (Vv dead after vn/s)
    short* Vw    = (short*)(smem + 30464);    // [48][136] muW
    short* vnb   = (short*)(smem + 43520);    // [16][136]
    short* sb    = (short*)(smem + 47872);    // [16][128]
    int t = threadIdx.x;
    int wv = t >> 6, lane = t & 63, quad = lane >> 4, l16 = lane & 15;
    int a0 = blockIdx.x * 16;

    // ---- stage 0: post-gather state into LDS (coalesced f32+delta) ----
    #pragma unroll
    for (int k = 0; k < 12; ++k) {
        int idx = k * 512 + t;                // 6144 = 48x128
        int row = idx >> 7, c = idx & 127;
        int g = (a0 * 3 + row) * 128 + c;
        ms[row * 136 + c] = f2bf(mu_ro[g] + bf2f(dmug[g]));
    }
    #pragma unroll
    for (int k = 0; k < 4; ++k) {
        int idx = k * 512 + t;                // 2048 = 16x128
        int row = idx >> 7, c = idx & 127;
        int g = (a0 + row) * 128 + c;
        qtile[row * 136 + c] = f2bf(q_ro[g] + bf2f(dqg[g]));
    }
    __syncthreads();                          // (1)

    // ---- stage A: mu @ Wv (M=48, N=256, K=128); wave wv: cols [wv*32, +32) ----
    {
        floatx4 acc[3][2];
        #pragma unroll
        for (int mt = 0; mt < 3; ++mt)
            #pragma unroll
            for (int nt = 0; nt < 2; ++nt) acc[mt][nt] = {0.f, 0.f, 0.f, 0.f};
        #pragma unroll
        for (int kk = 0; kk < 4; ++kk) {
            short8 a[3];
            #pragma unroll
            for (int mt = 0; mt < 3; ++mt)
                a[mt] = *(const short8*)(ms + (mt * 16 + l16) * 136 + kk * 32 + quad * 8);
            #pragma unroll
            for (int nt = 0; nt < 2; ++nt) {
                short8 b = *(const short8*)(Wvsw + ((wv * 2 + nt) * 4 + kk) * 512 + lane * 8);
                #pragma unroll
                for (int mt = 0; mt < 3; ++mt)
                    acc[mt][nt] = __builtin_amdgcn_mfma_f32_16x16x32_bf16(a[mt], b, acc[mt][nt], 0, 0, 0);
            }
        }
        #pragma unroll
        for (int mt = 0; mt < 3; ++mt)
            #pragma unroll
            for (int nt = 0; nt < 2; ++nt)
                #pragma unroll
                for (int r = 0; r < 4; ++r) {
                    int row = mt * 16 + quad * 4 + r;
                    int col = wv * 32 + nt * 16 + l16;
                    short v = f2bf(acc[mt][nt][r]);
                    if (col < 128) Vv[row * 136 + col] = v;
                    else           Vw[row * 136 + col - 128] = v;
                }
    }
    __syncthreads();                          // (2)
    // ---- vn, s ----
    #pragma unroll
    for (int k = 0; k < 4; ++k) {
        int idx = k * 512 + t;
        int a = idx >> 7, c = idx & 127;
        float v0 = bf2f(Vv[(a * 3 + 0) * 136 + c]);
        float v1 = bf2f(Vv[(a * 3 + 1) * 136 + c]);
        float v2 = bf2f(Vv[(a * 3 + 2) * 136 + c]);
        float w0 = bf2f(Vw[(a * 3 + 0) * 136 + c]);
        float w1 = bf2f(Vw[(a * 3 + 1) * 136 + c]);
        float w2 = bf2f(Vw[(a * 3 + 2) * 136 + c]);
        vnb[a * 136 + c] = f2bf(sqrtf(v0 * v0 + v1 * v1 + v2 * v2 + 1e-8f));
        sb[a * 128 + c]  = f2bf(v0 * w0 + v1 * w1 + v2 * w2);
    }
    __syncthreads();                          // (3) — last Vv reads done; hs alias free
    // ---- stage B1: h = silu([q|vn] @ W1 + b1), K=256; wave wv: cols [wv*16,+16) ----
    {
        floatx4 acc0 = {0.f, 0.f, 0.f, 0.f};
        #pragma unroll
        for (int kk = 0; kk < 8; ++kk) {
            short8 a;
            if (kk < 4)
                a = *(const short8*)(qtile + l16 * 136 + kk * 32 + quad * 8);
            else
                a = *(const short8*)(vnb + l16 * 136 + (kk - 4) * 32 + quad * 8);
            short8 b0 = *(const short8*)(W1sw + (wv * 8 + kk) * 512 + lane * 8);
            acc0 = __builtin_amdgcn_mfma_f32_16x16x32_bf16(a, b0, acc0, 0, 0, 0);
        }
        int n0 = wv * 16 + l16;
        float bia0 = b1[n0];
        #pragma unroll
        for (int r = 0; r < 4; ++r) {
            int m = quad * 4 + r;
            hs[m * 136 + n0] = f2bf(silu(acc0[r] + bia0));
        }
    }
    __syncthreads();                          // (4)
    // ---- stage B2: wave wv owns cols wv*16..+15; SINGLE master RMW epilogue ----
    {
        floatx4 accB[3];
        #pragma unroll
        for (int c = 0; c < 3; ++c) accB[c] = {0.f, 0.f, 0.f, 0.f};
        #pragma unroll
        for (int kk = 0; kk < 4; ++kk) {
            short8 a = *(const short8*)(hs + l16 * 136 + kk * 32 + quad * 8);
            #pragma unroll
            for (int c = 0; c < 3; ++c) {
                short8 b = *(const short8*)(W2sw + ((c * 8 + wv) * 4 + kk) * 512 + lane * 8);
                accB[c] = __builtin_amdgcn_mfma_f32_16x16x32_bf16(a, b, accB[c], 0, 0, 0);
            }
        }
        int co = wv * 16 + l16;
        float bq_  = b2[co];
        float bm_  = b2[128 + co];
        float bqm_ = b2[256 + co];
        #pragma unroll
        for (int r = 0; r < 4; ++r) {
            int m = quad * 4 + r;
            int ga = a0 + m;
            float dq   = accB[0][r] + bq_;
            float dmu  = accB[1][r] + bm_;
            float dqmu = accB[2][r] + bqm_;
            float sv = bf2f(sb[m * 128 + co]);
            int gq = ga * 128 + co;
            float qn = (q[gq] + bf2f(dqg[gq])) + dq + dqmu * sv;
            q[gq] = qn;
            qtile[m * 136 + co] = f2bf(qn);
            float mn[3];
            #pragma unroll
            for (int d = 0; d < 3; ++d) {
                int gm = (ga * 3 + d) * 128 + co;
                float mw = bf2f(Vw[(m * 3 + d) * 136 + co]);
                mn[d] = (mu[gm] + bf2f(dmug[gm])) + dmu * mw;
                mu[gm] = mn[d];
            }
            unsigned lo = (unsigned)(unsigned short)f2bf(mn[0]) |
                          ((unsigned)(unsigned short)f2bf(mn[1]) << 16);
            *(unsigned*)(xmu + (size_t)gq * 12 + 4) = lo;
            *(short*)(xmu + (size_t)gq * 12 + 8) = f2bf(mn[2]);
        }
    }
    if (!do_x) return;
    __syncthreads();                          // (5) qtile post-mix complete; hs free
    // ---- X-stage 1 ----
    {
        floatx4 acc0 = {0.f, 0.f, 0.f, 0.f};
        #pragma unroll
        for (int kk = 0; kk < 4; ++kk) {
            short8 a  = *(const short8*)(qtile + l16 * 136 + kk * 32 + quad * 8);
            short8 b0 = *(const short8*)(xW1sw + (wv * 4 + kk) * 512 + lane * 8);
            acc0 = __builtin_amdgcn_mfma_f32_16x16x32_bf16(a, b0, acc0, 0, 0, 0);
        }
        int n0 = wv * 16 + l16;
        float bia0 = xb1[n0];
        #pragma unroll
        for (int r = 0; r < 4; ++r) {
            int m = quad * 4 + r;
            hs[m * 136 + n0] = f2bf(silu(acc0[r] + bia0));
        }
    }
    __syncthreads();                          // (6)
    // ---- X-stage 2: x -> xmu x-bytes ----
    {
        floatx4 acc[3];
        #pragma unroll
        for (int jj = 0; jj < 3; ++jj) acc[jj] = {0.f, 0.f, 0.f, 0.f};
        #pragma unroll
        for (int kk = 0; kk < 4; ++kk) {
            short8 a = *(const short8*)(hs + l16 * 136 + kk * 32 + quad * 8);
            #pragma unroll
            for (int jj = 0; jj < 3; ++jj) {
                short8 b = *(const short8*)(xW2sw + ((wv * 3 + jj) * 4 + kk) * 512 + lane * 8);
                acc[jj] = __builtin_amdgcn_mfma_f32_16x16x32_bf16(a, b, acc[jj], 0, 0, 0);
            }
        }
        #pragma unroll
        for (int jj = 0; jj < 3; ++jj) {
            int n = wv * 48 + jj * 16 + l16;
            float bia = xb2[n];
            #pragma unroll
            for (int r = 0; r < 4; ++r) {
                int m = quad * 4 + r;
                xmu[(size_t)((a0 + m) * 128 + (n & 127)) * 12 + (n >> 7)] =
                    f2fp8(acc[jj][r] + bia);
            }
        }
    }
}

extern "C" void kernel_launch(void* const* d_in, const int* in_sizes, int n_in,
                              void* d_out, int out_size, void* d_ws, size_t ws_size,
                              hipStream_t stream) {
    const float* feat = (const float*)d_in[0];
    const float* dist = (const float*)d_in[1];
    const float* vec  = (const float*)d_in[2];
    const float* cut  = (const float*)d_in[3];
    const float* rbfs = (const float*)d_in[4];
    const float* fW   = (const float*)d_in[5];
    const float* fb   = (const float*)d_in[6];
    const float* iW1  = (const float*)d_in[7];
    const float* ib1  = (const float*)d_in[8];
    const float* iW2  = (const float*)d_in[9];
    const float* ib2  = (const float*)d_in[10];
    const float* mWv  = (const float*)d_in[11];
    const float* mW1  = (const float*)d_in[12];
    const float* mb1  = (const float*)d_in[13];
    const float* mW2  = (const float*)d_in[14];
    const float* mb2  = (const float*)d_in[15];
    const int* idx_i  = (const int*)d_in[16];
    const int* idx_j  = (const int*)d_in[17];

    float* q  = (float*)d_out;                 // 8192*128
    float* mu = (float*)d_out + NA * 128;      // 8192*3*128

    char* w = (char*)d_ws;
    unsigned char* xmu = (unsigned char*)(w);   // 12,582,912 (NA*128*12)
    short* dqg     = (short*)(w + 12582912);    // 2,097,152
    short* q_bf    = (short*)(w + 14680064);    // 2,097,152 (k_x input only)
    short* dmug    = (short*)(w + 16777216);    // 6,291,456
    short* W1t     = (short*)(w + 23068672);    // 163,840   swizzled
    short* W2t     = (short*)(w + 23232512);    // 491,520   swizzled
    short* Wvt     = (short*)(w + 23724032);    // 327,680   swizzled
    short* mW1t    = (short*)(w + 24051712);    // 327,680   swizzled
    short* mW2t    = (short*)(w + 24379392);    // 491,520   swizzled
    short* fWt     = (short*)(w + 24870912);    // 122,880   swizzled
    int*   counts  = (int*)(w + 24993792);      // 32,768
    int*   cursor  = (int*)(w + 25026560);      // 32,768
    int*   offs    = (int*)(w + 25059328);      // 32,772 (NA+1)
    int*   jcsr    = (int*)(w + 25092112);      // 262,144
    float* cut_csr = (float*)(w + 25354256);    // 262,208 (NP+16)
    float4* dir_csr= (float4*)(w + 25616464);   // 1,048,576 (16-aligned)
    short* rbf_c   = (short*)(w + 26665040);    // 4,195,328 (NP+16)x32

    k_tconv_all<<<(962560 + 255) / 256, 256, 0, stream>>>(iW1, iW2, mWv, mW1, mW2, fW,
                                                          W1t, W2t, Wvt, mW1t, mW2t, fWt);
    k_init<<<NA * 384 / 256, 256, 0, stream>>>(feat, q, mu, q_bf, (unsigned*)xmu,
                                               counts, cursor, cut_csr, rbf_c);
    k_hist<<<NP / 256, 256, 0, stream>>>(idx_i, counts);
    k_scan<<<1, 1024, 0, stream>>>(counts, offs);
    k_fillprep<<<NP / 256, 256, 0, stream>>>(idx_i, idx_j, offs, cursor, cut, dist, vec,
                                             rbfs, jcsr, cut_csr, dir_csr, rbf_c);

    k_x<<<NA / 16, 256, 0, stream>>>(q_bf, W1t, W2t, ib1, ib2, xmu);
    for (int b = 0; b < 5; ++b) {
        int bn = (b + 1) % 5;
        k_gather<<<NA / 2, 256, 0, stream>>>(xmu, rbf_c, fWt + b * 12288,
                                             fb + b * 384, jcsr, cut_csr, dir_csr,
                                             offs, dqg, dmug);
        k_mixx<<<NA / 16, 512, 0, stream>>>(mu, dmug, q, dqg,
                                            Wvt + b * 32768,
                                            mW1t + b * 32768, mW2t + b * 49152,
                                            mb1 + b * 128, mb2 + b * 384,
                                            q, mu, xmu,
                                            W1t + bn * 16384, W2t + bn * 49152,
                                            ib1 + bn * 128, ib2 + bn * 384,
                                            (b < 4) ? 1 : 0);
    }
}

// Round 17
// 406.068 us; speedup vs baseline: 1.0556x; 1.0556x over previous
//
#include <hip/hip_runtime.h>
#include <hip/hip_bf16.h>

#define NA 8192
#define NP 65536
#define WROW 1920

typedef short short8 __attribute__((ext_vector_type(8)));
typedef short short4v __attribute__((ext_vector_type(4)));
typedef float floatx4 __attribute__((ext_vector_type(4)));
typedef unsigned uint3v __attribute__((ext_vector_type(3)));

static __device__ __forceinline__ short f2bf(float f) {
    union { float f; unsigned u; } v; v.f = f;
    unsigned r = v.u + 0x7FFF + ((v.u >> 16) & 1);
    return (short)(r >> 16);
}
static __device__ __forceinline__ float bf2f(short s) {
    union { unsigned u; float f; } v;
    v.u = ((unsigned)(unsigned short)s) << 16;
    return v.f;
}
static __device__ __forceinline__ unsigned char f2fp8(float f) {
    int p = __builtin_amdgcn_cvt_pk_fp8_f32(f, 0.f, 0, false);
    return (unsigned char)(p & 0xFF);
}
static __device__ __forceinline__ float fp82f(unsigned char b) {
    return __builtin_amdgcn_cvt_f32_fp8((int)b, 0);
}
static __device__ __forceinline__ float silu(float v) {
    return v / (1.f + __expf(-v));
}

// swizzle one element: dst[idx] in MFMA-fragment order from src[b][K][N]
static __device__ __forceinline__ void swz(const float* __restrict__ src,
                                           short* __restrict__ dst,
                                           int K, int N, int idx) {
    int kn = K * N;
    int b = idx / kn;
    int r = idx - b * kn;
    int tile = r >> 9, li = r & 511;
    int lane = li >> 3, bb = li & 7;
    int Kt = K >> 5;
    int nt = tile / Kt, kt = tile - nt * Kt;
    int k = kt * 32 + (lane >> 4) * 8 + bb;
    int n = nt * 16 + (lane & 15);
    dst[idx] = f2bf(src[b * kn + k * N + n]);
}

// ---------------- all weight converts in one launch ----------------
__global__ __launch_bounds__(256) void k_tconv_all(const float* __restrict__ iW1,
                                                   const float* __restrict__ iW2,
                                                   const float* __restrict__ mWv,
                                                   const float* __restrict__ mW1,
                                                   const float* __restrict__ mW2,
                                                   const float* __restrict__ fW,
                                                   short* __restrict__ W1t,
                                                   short* __restrict__ W2t,
                                                   short* __restrict__ Wvt,
                                                   short* __restrict__ mW1t,
                                                   short* __restrict__ mW2t,
                                                   short* __restrict__ fWt) {
    int idx = blockIdx.x * 256 + threadIdx.x;
    if (idx < 81920)       { swz(iW1, W1t, 128, 128, idx); return; }
    idx -= 81920;
    if (idx < 245760)      { swz(iW2, W2t, 128, 384, idx); return; }
    idx -= 245760;
    if (idx < 163840)      { swz(mWv, Wvt, 128, 256, idx); return; }
    idx -= 163840;
    if (idx < 163840)      { swz(mW1, mW1t, 256, 128, idx); return; }
    idx -= 163840;
    if (idx < 245760)      { swz(mW2, mW2t, 128, 384, idx); return; }
    idx -= 245760;
    if (idx < 61440) {
        int b = idx / 12288;
        int r = idx - b * 12288;
        int nt = r >> 9;
        int li = r & 511;
        int lane = li >> 3, bb = li & 7;
        int k = (lane >> 4) * 8 + bb;
        int n = nt * 16 + (lane & 15);
        fWt[idx] = (k < 20) ? f2bf(fW[k * WROW + b * 384 + n]) : (short)0;
    }
}

// ---------------- init (+ CSR pad rows) ----------------
// xmu record (12B per (atom,feature)): {x0,x1,x2,pad, mu0, mu1, mu2, pad2}
__global__ __launch_bounds__(256) void k_init(const float* __restrict__ feat,
                                              float* __restrict__ q,
                                              float* __restrict__ mu,
                                              short* __restrict__ q_bf,
                                              unsigned* __restrict__ xmu_u,
                                              int* __restrict__ counts,
                                              int* __restrict__ cursor,
                                              float* __restrict__ cut_csr,
                                              short* __restrict__ rbf_c) {
    int idx = blockIdx.x * 256 + threadIdx.x;     // 0 .. NA*384-1
    if (idx < NA * 128) { float v = feat[idx]; q[idx] = v; q_bf[idx] = f2bf(v); }
    mu[idx] = 0.f;
    xmu_u[idx] = 0;                               // NA*128*12 bytes == NA*384 uints
    if (idx < NA) { counts[idx] = 0; cursor[idx] = 0; }
    if (idx < 16) {
        cut_csr[NP + idx] = 0.f;
        #pragma unroll
        for (int k = 0; k < 32; ++k) rbf_c[(NP + idx) * 32 + k] = 0;
    }
}

// ---------------- CSR build ----------------
__global__ __launch_bounds__(256) void k_hist(const int* __restrict__ idx_i,
                                              int* __restrict__ counts) {
    int p = blockIdx.x * 256 + threadIdx.x;
    if (p < NP) atomicAdd(&counts[idx_i[p]], 1);
}

__global__ __launch_bounds__(1024) void k_scan(const int* __restrict__ counts,
                                               int* __restrict__ offs) {
    __shared__ int sums[1024];
    int t = threadIdx.x;
    int local[8];
    int s = 0;
    #pragma unroll
    for (int k = 0; k < 8; ++k) { local[k] = s; s += counts[t * 8 + k]; }
    sums[t] = s;
    __syncthreads();
    for (int off = 1; off < 1024; off <<= 1) {
        int v = sums[t];
        int u = (t >= off) ? sums[t - off] : 0;
        __syncthreads();
        sums[t] = v + u;
        __syncthreads();
    }
    int base = (t > 0) ? sums[t - 1] : 0;
    #pragma unroll
    for (int k = 0; k < 8; ++k) offs[t * 8 + k] = base + local[k];
    if (t == 1023) offs[NA] = sums[1023];
}

// fill + prep fused: scatter pair p to CSR slot e and write all per-pair data.
__global__ __launch_bounds__(256) void k_fillprep(const int* __restrict__ idx_i,
                                                  const int* __restrict__ idx_j,
                                                  const int* __restrict__ offs,
                                                  int* __restrict__ cursor,
                                                  const float* __restrict__ cut,
                                                  const float* __restrict__ dist,
                                                  const float* __restrict__ vec,
                                                  const float* __restrict__ rbfs,
                                                  int* __restrict__ jcsr,
                                                  float* __restrict__ cut_csr,
                                                  float4* __restrict__ dir_csr,
                                                  short* __restrict__ rbf_c) {
    int p = blockIdx.x * 256 + threadIdx.x;
    if (p >= NP) return;
    int i = idx_i[p];
    int pos = atomicAdd(&cursor[i], 1);
    int e = offs[i] + pos;
    jcsr[e] = idx_j[p];
    float c = cut[p];
    cut_csr[e] = c;
    float invd = 1.f / dist[p];
    float4 d;
    d.x = vec[p * 3 + 0] * invd;
    d.y = vec[p * 3 + 1] * invd;
    d.z = vec[p * 3 + 2] * invd;
    d.w = 0.f;
    dir_csr[e] = d;
    #pragma unroll
    for (int k = 0; k < 20; ++k) rbf_c[e * 32 + k] = f2bf(rbfs[p * 20 + k] * c);
    #pragma unroll
    for (int k = 20; k < 32; ++k) rbf_c[e * 32 + k] = 0;
}

// ---------------- K1 (MFMA): x = silu(q@W1+b1)@W2+b2 -> xmu x-bytes (block 0 only) ----------------
__global__ __launch_bounds__(256) void k_x(const short* __restrict__ q_bf,
                                           const short* __restrict__ W1sw,
                                           const short* __restrict__ W2sw,
                                           const float* __restrict__ b1,
                                           const float* __restrict__ b2,
                                           unsigned char* __restrict__ xmu) {
    __shared__ __align__(16) short qtile[16 * 136];
    __shared__ __align__(16) short hs[16 * 136];
    int t = threadIdx.x;
    int wv = t >> 6, lane = t & 63, quad = lane >> 4, l16 = lane & 15;
    int a0 = blockIdx.x * 16;

    #pragma unroll
    for (int it = 0; it < 2; ++it) {
        int c = it * 256 + t;
        int row = c >> 5, col4 = c & 31;
        *(short4v*)(qtile + row * 136 + col4 * 4) =
            *(const short4v*)(q_bf + (a0 + row) * 128 + col4 * 4);
    }
    __syncthreads();

    floatx4 acc0 = {0.f, 0.f, 0.f, 0.f}, acc1 = {0.f, 0.f, 0.f, 0.f};
    #pragma unroll
    for (int kk = 0; kk < 4; ++kk) {
        short8 a  = *(const short8*)(qtile + l16 * 136 + kk * 32 + quad * 8);
        short8 b0 = *(const short8*)(W1sw + ((wv * 2 + 0) * 4 + kk) * 512 + lane * 8);
        short8 bq = *(const short8*)(W1sw + ((wv * 2 + 1) * 4 + kk) * 512 + lane * 8);
        acc0 = __builtin_amdgcn_mfma_f32_16x16x32_bf16(a, b0, acc0, 0, 0, 0);
        acc1 = __builtin_amdgcn_mfma_f32_16x16x32_bf16(a, bq, acc1, 0, 0, 0);
    }
    __syncthreads();
    {
        int n0 = wv * 32 + l16;
        float bia0 = b1[n0], bia1 = b1[n0 + 16];
        #pragma unroll
        for (int r = 0; r < 4; ++r) {
            int m = quad * 4 + r;
            hs[m * 136 + n0]      = f2bf(silu(acc0[r] + bia0));
            hs[m * 136 + n0 + 16] = f2bf(silu(acc1[r] + bia1));
        }
    }
    __syncthreads();
    floatx4 acc[6];
    #pragma unroll
    for (int jj = 0; jj < 6; ++jj) acc[jj] = {0.f, 0.f, 0.f, 0.f};
    #pragma unroll
    for (int kk = 0; kk < 4; ++kk) {
        short8 a = *(const short8*)(hs + l16 * 136 + kk * 32 + quad * 8);
        #pragma unroll
        for (int jj = 0; jj < 6; ++jj) {
            short8 b = *(const short8*)(W2sw + ((wv * 6 + jj) * 4 + kk) * 512 + lane * 8);
            acc[jj] = __builtin_amdgcn_mfma_f32_16x16x32_bf16(a, b, acc[jj], 0, 0, 0);
        }
    }
    #pragma unroll
    for (int jj = 0; jj < 6; ++jj) {
        int n = wv * 96 + jj * 16 + l16;
        float bia = b2[n];
        #pragma unroll
        for (int r = 0; r < 4; ++r) {
            int m = quad * 4 + r;
            xmu[(size_t)((a0 + m) * 128 + (n & 127)) * 12 + (n >> 7)] =
                f2fp8(acc[jj][r] + bia);
        }
    }
}

// ---------------- K2: per-atom gather -> bf16 deltas (R13 proven shape) ----------------
__global__ __launch_bounds__(256, 6) void k_gather(const unsigned char* __restrict__ xmu,
                                                   const short* __restrict__ rbf_c,
                                                   const short* __restrict__ fWt,   // swizzled
                                                   const float* __restrict__ fbp,   // fb + bo
                                                   const int* __restrict__ jcsr,
                                                   const float* __restrict__ cut_csr,
                                                   const float4* __restrict__ dir_csr,
                                                   const int* __restrict__ offs,
                                                   short* __restrict__ dqg,
                                                   short* __restrict__ dmug) {
    __shared__ short dlds[16 * 392];
    __shared__ float pm[4 * 128];
    int i = blockIdx.x;
    int t = threadIdx.x;
    int h = t >> 7;                             // pair-parity half
    int f = t & 127;                            // feature column
    int wv = t >> 6, lane = t & 63, quad = lane >> 4, l16 = lane & 15;
    int start = offs[i], end = offs[i + 1];
    float qa = 0.f, m0a = 0.f, m1a = 0.f, m2a = 0.f;

    for (int e0 = start; e0 < end; e0 += 16) {
        if (e0 > start) __syncthreads();        // protect dlds reuse
        // ---- phase 1: descriptors for rows e0..e0+15 (wave wv: cols wv*96..+95)
        short8 a = *(const short8*)(rbf_c + (e0 + l16) * 32 + quad * 8);
        float c0 = cut_csr[e0 + quad * 4 + 0];
        float c1 = cut_csr[e0 + quad * 4 + 1];
        float c2 = cut_csr[e0 + quad * 4 + 2];
        float c3 = cut_csr[e0 + quad * 4 + 3];
        #pragma unroll
        for (int nt = 0; nt < 6; ++nt) {
            int col = wv * 96 + nt * 16 + l16;
            short8 bfr = *(const short8*)(fWt + (wv * 6 + nt) * 512 + lane * 8);
            floatx4 z = {0.f, 0.f, 0.f, 0.f};
            floatx4 acc = __builtin_amdgcn_mfma_f32_16x16x32_bf16(a, bfr, z, 0, 0, 0);
            float fbv = fbp[col];
            dlds[(quad * 4 + 0) * 392 + col] = f2bf(acc[0] + fbv * c0);
            dlds[(quad * 4 + 1) * 392 + col] = f2bf(acc[1] + fbv * c1);
            dlds[(quad * 4 + 2) * 392 + col] = f2bf(acc[2] + fbv * c2);
            dlds[(quad * 4 + 3) * 392 + col] = f2bf(acc[3] + fbv * c3);
        }
        __syncthreads();
        // ---- phase 2: this half walks its parity of pairs, depth-1 prefetch
        int lim = (end < e0 + 16) ? end : (e0 + 16);
        int e = e0 + h;
        if (e < lim) {
            int jA = jcsr[e];
            float4 dirA = dir_csr[e];
            uint3v recA = *(const uint3v*)(xmu + (size_t)jA * 1536 + f * 12);
            for (; e < lim; e += 2) {
                uint3v rec = recA;
                float4 cdir = dirA;
                int en = e + 2;
                if (en < lim) {
                    int jn = jcsr[en];
                    dirA = dir_csr[en];
                    recA = *(const uint3v*)(xmu + (size_t)jn * 1536 + f * 12);
                }
                float x0 = fp82f((unsigned char)(rec.x & 0xFF));
                float x1 = fp82f((unsigned char)((rec.x >> 8) & 0xFF));
                float x2 = fp82f((unsigned char)((rec.x >> 16) & 0xFF));
                float u0 = bf2f((short)(rec.y & 0xFFFF));
                float u1 = bf2f((short)(rec.y >> 16));
                float u2 = bf2f((short)(rec.z & 0xFFFF));
                int le = e - e0;
                float wa = bf2f(dlds[le * 392 + f]);
                float wb = bf2f(dlds[le * 392 + 128 + f]);
                float wc = bf2f(dlds[le * 392 + 256 + f]);
                qa += x0 * wa;
                float xb = x1 * wb;
                float xc = x2 * wc;
                m0a += xb * cdir.x + xc * u0;
                m1a += xb * cdir.y + xc * u1;
                m2a += xb * cdir.z + xc * u2;
            }
        }
    }
    // ---- merge halves and stream deltas (no master access)
    if (h == 1) {
        pm[0 * 128 + f] = qa;
        pm[1 * 128 + f] = m0a;
        pm[2 * 128 + f] = m1a;
        pm[3 * 128 + f] = m2a;
    }
    __syncthreads();
    if (h == 0) {
        qa  += pm[0 * 128 + f];
        m0a += pm[1 * 128 + f];
        m1a += pm[2 * 128 + f];
        m2a += pm[3 * 128 + f];
        dqg[i * 128 + f]             = f2bf(qa);
        dmug[(i * 3 + 0) * 128 + f]  = f2bf(m0a);
        dmug[(i * 3 + 1) * 128 + f]  = f2bf(m1a);
        dmug[(i * 3 + 2) * 128 + f]  = f2bf(m2a);
    }
}

// ---------------- K3 (MFMA): gather-commit + mixv + mix2 + next-block x-MLP ----------------
// R17: stage 0 uses the EPILOGUE's thread mapping and keeps the f32 sums
// (master+delta) in registers -> epilogue re-reads of mu/dmug/q/dqg deleted
// (~25 MB/dispatch). Bit-identical numerics. (512,4): VGPR cap 128, no spill.
__global__ __launch_bounds__(512, 4) void k_mixx(const float* __restrict__ mu_ro,
                                                 const short* __restrict__ dmug,
                                                 const float* __restrict__ q_ro,
                                                 const short* __restrict__ dqg,
                                                 const short* __restrict__ Wvsw,
                                                 const short* __restrict__ W1sw,
                                                 const short* __restrict__ W2sw,
                                                 const float* __restrict__ b1,
                                                 const float* __restrict__ b2,
                                                 float* __restrict__ q,
                                                 float* __restrict__ mu,
                                                 unsigned char* __restrict__ xmu,
                                                 const short* __restrict__ xW1sw,
                                                 const short* __restrict__ xW2sw,
                                                 const float* __restrict__ xb1,
                                                 const float* __restrict__ xb2,
                                                 int do_x) {
    __shared__ __align__(16) char smem[51968];
    short* ms    = (short*)(smem);            // [48][136] post-gather mu (bf16)
    short* qtile = (short*)(smem + 13056);    // [16][136] post-gather q (then post-mix q)
    short* Vv    = (short*)(smem + 17408);    // [48][136] muV
    short* hs    = (short*)(smem + 17408);    // [16][136] alias (Vv dead after vn/s)
    short* Vw    = (short*)(smem + 30464);    // [48][136] muW
    short* vnb   = (short*)(smem + 43520);    // [16][136]
    short* sb    = (short*)(smem + 47872);    // [16][128]
    int t = threadIdx.x;
    int wv = t >> 6, lane = t & 63, quad = lane >> 4, l16 = lane & 15;
    int a0 = blockIdx.x * 16;
    int co = wv * 16 + l16;

    // ---- stage 0: post-gather state -> LDS, f32 sums kept in registers
    //      (epilogue mapping: thread owns rows quad*4+r, col co, all 3 dims)
    float qnf[4];
    float mnf[4][3];
    #pragma unroll
    for (int r = 0; r < 4; ++r) {
        int m = quad * 4 + r;
        int ga = a0 + m;
        int gq = ga * 128 + co;
        qnf[r] = q_ro[gq] + bf2f(dqg[gq]);
        qtile[m * 136 + co] = f2bf(qnf[r]);
        #pragma unroll
        for (int d = 0; d < 3; ++d) {
            int gm = (ga * 3 + d) * 128 + co;
            mnf[r][d] = mu_ro[gm] + bf2f(dmug[gm]);
            ms[(m * 3 + d) * 136 + co] = f2bf(mnf[r][d]);
        }
    }
    __syncthreads();                          // (1)

    // ---- stage A: mu @ Wv (M=48, N=256, K=128); wave wv: cols [wv*32, +32) ----
    {
        floatx4 acc[3][2];
        #pragma unroll
        for (int mt = 0; mt < 3; ++mt)
            #pragma unroll
            for (int nt = 0; nt < 2; ++nt) acc[mt][nt] = {0.f, 0.f, 0.f, 0.f};
        #pragma unroll
        for (int kk = 0; kk < 4; ++kk) {
            short8 a[3];
            #pragma unroll
            for (int mt = 0; mt < 3; ++mt)
                a[mt] = *(const short8*)(ms + (mt * 16 + l16) * 136 + kk * 32 + quad * 8);
            #pragma unroll
            for (int nt = 0; nt < 2; ++nt) {
                short8 b = *(const short8*)(Wvsw + ((wv * 2 + nt) * 4 + kk) * 512 + lane * 8);
                #pragma unroll
                for (int mt = 0; mt < 3; ++mt)
                    acc[mt][nt] = __builtin_amdgcn_mfma_f32_16x16x32_bf16(a[mt], b, acc[mt][nt], 0, 0, 0);
            }
        }
        #pragma unroll
        for (int mt = 0; mt < 3; ++mt)
            #pragma unroll
            for (int nt = 0; nt < 2; ++nt)
                #pragma unroll
                for (int r = 0; r < 4; ++r) {
                    int row = mt * 16 + quad * 4 + r;
                    int col = wv * 32 + nt * 16 + l16;
                    short v = f2bf(acc[mt][nt][r]);
                    if (col < 128) Vv[row * 136 + col] = v;
                    else           Vw[row * 136 + col - 128] = v;
                }
    }
    __syncthreads();                          // (2)
    // ---- vn, s ----
    #pragma unroll
    for (int k = 0; k < 4; ++k) {
        int idx = k * 512 + t;
        int a = idx >> 7, c = idx & 127;
        float v0 = bf2f(Vv[(a * 3 + 0) * 136 + c]);
        float v1 = bf2f(Vv[(a * 3 + 1) * 136 + c]);
        float v2 = bf2f(Vv[(a * 3 + 2) * 136 + c]);
        float w0 = bf2f(Vw[(a * 3 + 0) * 136 + c]);
        float w1 = bf2f(Vw[(a * 3 + 1) * 136 + c]);
        float w2 = bf2f(Vw[(a * 3 + 2) * 136 + c]);
        vnb[a * 136 + c] = f2bf(sqrtf(v0 * v0 + v1 * v1 + v2 * v2 + 1e-8f));
        sb[a * 128 + c]  = f2bf(v0 * w0 + v1 * w1 + v2 * w2);
    }
    __syncthreads();                          // (3) — last Vv reads done; hs alias free
    // ---- stage B1: h = silu([q|vn] @ W1 + b1), K=256; wave wv: cols [wv*16,+16) ----
    {
        floatx4 acc0 = {0.f, 0.f, 0.f, 0.f};
        #pragma unroll
        for (int kk = 0; kk < 8; ++kk) {
            short8 a;
            if (kk < 4)
                a = *(const short8*)(qtile + l16 * 136 + kk * 32 + quad * 8);
            else
                a = *(const short8*)(vnb + l16 * 136 + (kk - 4) * 32 + quad * 8);
            short8 b0 = *(const short8*)(W1sw + (wv * 8 + kk) * 512 + lane * 8);
            acc0 = __builtin_amdgcn_mfma_f32_16x16x32_bf16(a, b0, acc0, 0, 0, 0);
        }
        int n0 = wv * 16 + l16;
        float bia0 = b1[n0];
        #pragma unroll
        for (int r = 0; r < 4; ++r) {
            int m = quad * 4 + r;
            hs[m * 136 + n0] = f2bf(silu(acc0[r] + bia0));
        }
    }
    __syncthreads();                          // (4)
    // ---- stage B2: wave wv owns cols wv*16..+15; register-carried master RMW ----
    {
        floatx4 accB[3];
        #pragma unroll
        for (int c = 0; c < 3; ++c) accB[c] = {0.f, 0.f, 0.f, 0.f};
        #pragma unroll
        for (int kk = 0; kk < 4; ++kk) {
            short8 a = *(const short8*)(hs + l16 * 136 + kk * 32 + quad * 8);
            #pragma unroll
            for (int c = 0; c < 3; ++c) {
                short8 b = *(const short8*)(W2sw + ((c * 8 + wv) * 4 + kk) * 512 + lane * 8);
                accB[c] = __builtin_amdgcn_mfma_f32_16x16x32_bf16(a, b, accB[c], 0, 0, 0);
            }
        }
        float bq_  = b2[co];
        float bm_  = b2[128 + co];
        float bqm_ = b2[256 + co];
        #pragma unroll
        for (int r = 0; r < 4; ++r) {
            int m = quad * 4 + r;
            int ga = a0 + m;
            float dq   = accB[0][r] + bq_;
            float dmu  = accB[1][r] + bm_;
            float dqmu = accB[2][r] + bqm_;
            float sv = bf2f(sb[m * 128 + co]);
            int gq = ga * 128 + co;
            float qn = qnf[r] + dq + dqmu * sv;
            q[gq] = qn;
            qtile[m * 136 + co] = f2bf(qn);
            float mn[3];
            #pragma unroll
            for (int d = 0; d < 3; ++d) {
                int gm = (ga * 3 + d) * 128 + co;
                float mw = bf2f(Vw[(m * 3 + d) * 136 + co]);
                mn[d] = mnf[r][d] + dmu * mw;
                mu[gm] = mn[d];
            }
            unsigned lo = (unsigned)(unsigned short)f2bf(mn[0]) |
                          ((unsigned)(unsigned short)f2bf(mn[1]) << 16);
            *(unsigned*)(xmu + (size_t)gq * 12 + 4) = lo;
            *(short*)(xmu + (size_t)gq * 12 + 8) = f2bf(mn[2]);
        }
    }
    if (!do_x) return;
    __syncthreads();                          // (5) qtile post-mix complete; hs free
    // ---- X-stage 1 ----
    {
        floatx4 acc0 = {0.f, 0.f, 0.f, 0.f};
        #pragma unroll
        for (int kk = 0; kk < 4; ++kk) {
            short8 a  = *(const short8*)(qtile + l16 * 136 + kk * 32 + quad * 8);
            short8 b0 = *(const short8*)(xW1sw + (wv * 4 + kk) * 512 + lane * 8);
            acc0 = __builtin_amdgcn_mfma_f32_16x16x32_bf16(a, b0, acc0, 0, 0, 0);
        }
        int n0 = wv * 16 + l16;
        float bia0 = xb1[n0];
        #pragma unroll
        for (int r = 0; r < 4; ++r) {
            int m = quad * 4 + r;
            hs[m * 136 + n0] = f2bf(silu(acc0[r] + bia0));
        }
    }
    __syncthreads();                          // (6)
    // ---- X-stage 2: x -> xmu x-bytes ----
    {
        floatx4 acc[3];
        #pragma unroll
        for (int jj = 0; jj < 3; ++jj) acc[jj] = {0.f, 0.f, 0.f, 0.f};
        #pragma unroll
        for (int kk = 0; kk < 4; ++kk) {
            short8 a = *(const short8*)(hs + l16 * 136 + kk * 32 + quad * 8);
            #pragma unroll
            for (int jj = 0; jj < 3; ++jj) {
                short8 b = *(const short8*)(xW2sw + ((wv * 3 + jj) * 4 + kk) * 512 + lane * 8);
                acc[jj] = __builtin_amdgcn_mfma_f32_16x16x32_bf16(a, b, acc[jj], 0, 0, 0);
            }
        }
        #pragma unroll
        for (int jj = 0; jj < 3; ++jj) {
            int n = wv * 48 + jj * 16 + l16;
            float bia = xb2[n];
            #pragma unroll
            for (int r = 0; r < 4; ++r) {
                int m = quad * 4 + r;
                xmu[(size_t)((a0 + m) * 128 + (n & 127)) * 12 + (n >> 7)] =
                    f2fp8(acc[jj][r] + bia);
            }
        }
    }
}

extern "C" void kernel_launch(void* const* d_in, const int* in_sizes, int n_in,
                              void* d_out, int out_size, void* d_ws, size_t ws_size,
                              hipStream_t stream) {
    const float* feat = (const float*)d_in[0];
    const float* dist = (const float*)d_in[1];
    const float* vec  = (const float*)d_in[2];
    const float* cut  = (const float*)d_in[3];
    const float* rbfs = (const float*)d_in[4];
    const float* fW   = (const float*)d_in[5];
    const float* fb   = (const float*)d_in[6];
    const float* iW1  = (const float*)d_in[7];
    const float* ib1  = (const float*)d_in[8];
    const float* iW2  = (const float*)d_in[9];
    const float* ib2  = (const float*)d_in[10];
    const float* mWv  = (const float*)d_in[11];
    const float* mW1  = (const float*)d_in[12];
    const float* mb1  = (const float*)d_in[13];
    const float* mW2  = (const float*)d_in[14];
    const float* mb2  = (const float*)d_in[15];
    const int* idx_i  = (const int*)d_in[16];
    const int* idx_j  = (const int*)d_in[17];

    float* q  = (float*)d_out;                 // 8192*128
    float* mu = (float*)d_out + NA * 128;      // 8192*3*128

    char* w = (char*)d_ws;
    unsigned char* xmu = (unsigned char*)(w);   // 12,582,912 (NA*128*12)
    short* dqg     = (short*)(w + 12582912);    // 2,097,152
    short* q_bf    = (short*)(w + 14680064);    // 2,097,152 (k_x input only)
    short* dmug    = (short*)(w + 16777216);    // 6,291,456
    short* W1t     = (short*)(w + 23068672);    // 163,840   swizzled
    short* W2t     = (short*)(w + 23232512);    // 491,520   swizzled
    short* Wvt     = (short*)(w + 23724032);    // 327,680   swizzled
    short* mW1t    = (short*)(w + 24051712);    // 327,680   swizzled
    short* mW2t    = (short*)(w + 24379392);    // 491,520   swizzled
    short* fWt     = (short*)(w + 24870912);    // 122,880   swizzled
    int*   counts  = (int*)(w + 24993792);      // 32,768
    int*   cursor  = (int*)(w + 25026560);      // 32,768
    int*   offs    = (int*)(w + 25059328);      // 32,772 (NA+1)
    int*   jcsr    = (int*)(w + 25092112);      // 262,144
    float* cut_csr = (float*)(w + 25354256);    // 262,208 (NP+16)
    float4* dir_csr= (float4*)(w + 25616464);   // 1,048,576 (16-aligned)
    short* rbf_c   = (short*)(w + 26665040);    // 4,195,328 (NP+16)x32

    k_tconv_all<<<(962560 + 255) / 256, 256, 0, stream>>>(iW1, iW2, mWv, mW1, mW2, fW,
                                                          W1t, W2t, Wvt, mW1t, mW2t, fWt);
    k_init<<<NA * 384 / 256, 256, 0, stream>>>(feat, q, mu, q_bf, (unsigned*)xmu,
                                               counts, cursor, cut_csr, rbf_c);
    k_hist<<<NP / 256, 256, 0, stream>>>(idx_i, counts);
    k_scan<<<1, 1024, 0, stream>>>(counts, offs);
    k_fillprep<<<NP / 256, 256, 0, stream>>>(idx_i, idx_j, offs, cursor, cut, dist, vec,
                                             rbfs, jcsr, cut_csr, dir_csr, rbf_c);

    k_x<<<NA / 16, 256, 0, stream>>>(q_bf, W1t, W2t, ib1, ib2, xmu);
    for (int b = 0; b < 5; ++b) {
        int bn = (b + 1) % 5;
        k_gather<<<NA, 256, 0, stream>>>(xmu, rbf_c, fWt + b * 12288,
                                         fb + b * 384, jcsr, cut_csr, dir_csr,
                                         offs, dqg, dmug);
        k_mixx<<<NA / 16, 512, 0, stream>>>(mu, dmug, q, dqg,
                                            Wvt + b * 32768,
                                            mW1t + b * 32768, mW2t + b * 49152,
                                            mb1 + b * 128, mb2 + b * 384,
                                            q, mu, xmu,
                                            W1t + bn * 16384, W2t + bn * 49152,
                                            ib1 + bn * 128, ib2 + bn * 384,
                                            (b < 4) ? 1 : 0);
    }
}